// Round 14
// baseline (128.831 us; speedup 1.0000x reference)
//
#include <hip/hip_runtime.h>

// RNN scan: h_{t+1} = relu(W_hh @ h_t + x_t * w_x), out = W_hy @ h_T
// B=8192, T=512, H=64.
// Round 14: ZERO-EXCHANGE (r13 design) with ZERO inline asm (r13's NaN is
// consistent only with register corruption in its 16x8 unrolled asm pack;
// the permuted-tile algebra is verified by derivation + r10's layout proof).
// One wave per 16 batch cols; wave computes all 64 h rows as 4 M-tiles of
// 16 PERMUTED rows:  I_m[i] = 32*(m>>1) + 8*(i>>2) + 4*(m&1) + (i&3)
// => lane (c,g)'s 16 C slots (tile m, reg r -> row I_m[4g+r]) are exactly
// rows {8g..8g+7} u {32+8g..32+8g+7} of col c == its OWN B-fragments for
// both K-halves next step:
//   Bv0 = {pk(a0[0],a0[1]), pk(a0[2],a0[3]), pk(a1[0],a1[1]), pk(a1[2],a1[3])}
//   Bv1 = {same with a2, a3}
// Pack = 8x pk2_relu (pure C++, r1-r7-verified). No LDS/barrier/shuffle.
// Per step: 8x mfma_f32_16x16x32_bf16 = 4 independent depth-2 chains.
// Layouts (r10-verified): A row=lane&15, k=8*(lane>>4)+e (A/B k-maps cancel);
//   B col=lane&15, k=8*(lane>>4)+e; C col=lane&15, row=4*(lane>>4)+reg.

typedef __bf16 bf16x8 __attribute__((ext_vector_type(8)));
typedef float f32x4 __attribute__((ext_vector_type(4)));
typedef unsigned int u32x4 __attribute__((ext_vector_type(4)));

#define RNN_B 8192
#define RNN_T 512
#define RNN_H 64

__device__ __forceinline__ unsigned pk2_relu(float a, float b) {
  float ra = fmaxf(a, 0.0f), rb = fmaxf(b, 0.0f);
  unsigned short ua = __builtin_bit_cast(unsigned short, (__bf16)ra);
  unsigned short ub = __builtin_bit_cast(unsigned short, (__bf16)rb);
  return (unsigned)ua | ((unsigned)ub << 16);
}

__global__ __launch_bounds__(64, 1) void rnn_scan_kernel(
    const float* __restrict__ x,
    const float* __restrict__ Wxh,
    const float* __restrict__ Whh,
    const float* __restrict__ Why,
    float* __restrict__ out)
{
  const int lane = threadIdx.x;
  const int c    = lane & 15;      // batch col within wave
  const int g    = lane >> 4;      // lane group
  const int b0   = blockIdx.x * 16;

  // ---- A frags: A[m][kh], lane (c,g) = W_hh[I_m[c]][32kh + 8g + e] ----
  bf16x8 A[4][2];
#pragma unroll
  for (int m = 0; m < 4; ++m) {
    const int row = 32 * (m >> 1) + 8 * (c >> 2) + 4 * (m & 1) + (c & 3);
#pragma unroll
    for (int kh = 0; kh < 2; ++kh) {
      const float* wp = Whh + (size_t)row * RNN_H + 32 * kh + 8 * g;
      float4 w0 = *(const float4*)(wp);
      float4 w1 = *(const float4*)(wp + 4);
      bf16x8 f;
      f[0] = (__bf16)w0.x; f[1] = (__bf16)w0.y; f[2] = (__bf16)w0.z; f[3] = (__bf16)w0.w;
      f[4] = (__bf16)w1.x; f[5] = (__bf16)w1.y; f[6] = (__bf16)w1.z; f[7] = (__bf16)w1.w;
      A[m][kh] = f;
    }
  }

  // ---- w_x per C slot: tile m reg r -> row I_m[4g+r] ----
  f32x4 wx0, wx1, wx2, wx3;
#pragma unroll
  for (int r = 0; r < 4; ++r) {
    wx0[r] = Wxh[8 * g + r];
    wx1[r] = Wxh[8 * g + 4 + r];
    wx2[r] = Wxh[32 + 8 * g + r];
    wx3[r] = Wxh[32 + 8 * g + 4 + r];
  }

  const float* xrow = x + (size_t)(b0 + c) * RNN_T;
  float4 xc0 = *(const float4*)(xrow);
  float4 xc1 = *(const float4*)(xrow + 4);

  f32x4 a0 = {}, a1 = {}, a2 = {}, a3 = {};   // pre-relu h slots (4 tiles)
  u32x4 Bv0 = {}, Bv1 = {};                    // B frags (h_0 = 0)

  for (int tb = 0; tb < RNN_T; tb += 8) {
    const int tn = (tb + 8 < RNN_T) ? tb + 8 : tb;
    float4 xn0 = *(const float4*)(xrow + tn);
    float4 xn1 = *(const float4*)(xrow + tn + 4);
    const float xs[8] = {xc0.x, xc0.y, xc0.z, xc0.w, xc1.x, xc1.y, xc1.z, xc1.w};
#pragma unroll
    for (int j = 0; j < 8; ++j) {
      const float xv = xs[j];
      // 4 independent depth-2 chains; C-in = f32-exact x-term
      a0 = wx0 * xv; a1 = wx1 * xv; a2 = wx2 * xv; a3 = wx3 * xv;
      bf16x8 B0 = __builtin_bit_cast(bf16x8, Bv0);
      bf16x8 B1 = __builtin_bit_cast(bf16x8, Bv1);
      a0 = __builtin_amdgcn_mfma_f32_16x16x32_bf16(A[0][0], B0, a0, 0, 0, 0);
      a1 = __builtin_amdgcn_mfma_f32_16x16x32_bf16(A[1][0], B0, a1, 0, 0, 0);
      a2 = __builtin_amdgcn_mfma_f32_16x16x32_bf16(A[2][0], B0, a2, 0, 0, 0);
      a3 = __builtin_amdgcn_mfma_f32_16x16x32_bf16(A[3][0], B0, a3, 0, 0, 0);
      a0 = __builtin_amdgcn_mfma_f32_16x16x32_bf16(A[0][1], B1, a0, 0, 0, 0);
      a1 = __builtin_amdgcn_mfma_f32_16x16x32_bf16(A[1][1], B1, a1, 0, 0, 0);
      a2 = __builtin_amdgcn_mfma_f32_16x16x32_bf16(A[2][1], B1, a2, 0, 0, 0);
      a3 = __builtin_amdgcn_mfma_f32_16x16x32_bf16(A[3][1], B1, a3, 0, 0, 0);

      // pack in place: C slots ARE the next B frags (pure C++, no asm)
      Bv0[0] = pk2_relu(a0[0], a0[1]);
      Bv0[1] = pk2_relu(a0[2], a0[3]);
      Bv0[2] = pk2_relu(a1[0], a1[1]);
      Bv0[3] = pk2_relu(a1[2], a1[3]);
      Bv1[0] = pk2_relu(a2[0], a2[1]);
      Bv1[1] = pk2_relu(a2[2], a2[3]);
      Bv1[2] = pk2_relu(a3[0], a3[1]);
      Bv1[3] = pk2_relu(a3[2], a3[3]);
    }
    xc0 = xn0; xc1 = xn1;
  }

  // ---- epilogue: out[b] = sum_rows Why * relu(h_T) ----
  float pw = 0.0f;
#pragma unroll
  for (int r = 0; r < 4; ++r) {
    pw += Why[8 * g + r]          * fmaxf(a0[r], 0.0f);
    pw += Why[8 * g + 4 + r]      * fmaxf(a1[r], 0.0f);
    pw += Why[32 + 8 * g + r]     * fmaxf(a2[r], 0.0f);
    pw += Why[32 + 8 * g + 4 + r] * fmaxf(a3[r], 0.0f);
  }
  pw += __shfl_xor(pw, 16, 64);
  pw += __shfl_xor(pw, 32, 64);
  if (lane < 16) out[b0 + c] = pw;
}

extern "C" void kernel_launch(void* const* d_in, const int* in_sizes, int n_in,
                              void* d_out, int out_size, void* d_ws, size_t ws_size,
                              hipStream_t stream) {
  const float* x   = (const float*)d_in[0];
  const float* Wxh = (const float*)d_in[1];
  const float* Whh = (const float*)d_in[2];
  const float* Why = (const float*)d_in[3];
  float* out = (float*)d_out;
  (void)in_sizes; (void)n_in; (void)out_size; (void)d_ws; (void)ws_size;
  rnn_scan_kernel<<<dim3(RNN_B / 16), dim3(64), 0, stream>>>(x, Wxh, Whh, Why, out);
}